// Round 8
// baseline (337.206 us; speedup 1.0000x reference)
//
#include <hip/hip_runtime.h>
#include <hip/hip_bf16.h>

constexpr int B_ = 4;
constexpr int T_ = 2048;
constexpr int DIM_ = 1024;
constexpr int H_ = 8;
constexpr int D_ = 128;
constexpr int HDIM_ = H_ * D_;   // 1024

typedef __attribute__((ext_vector_type(8))) short bf16x8;
typedef __attribute__((ext_vector_type(8))) unsigned short ushort8;
typedef __attribute__((ext_vector_type(4))) float f32x4;
typedef __attribute__((ext_vector_type(16))) float f32x16;

#define ATTN_SCALE 0.08838834764831845f

__device__ __forceinline__ unsigned short f2bf(float x) {
    unsigned u = __float_as_uint(x);
    unsigned r = (u + 0x7FFFu + ((u >> 16) & 1u)) >> 16;
    return (unsigned short)r;
}
__device__ __forceinline__ float bf2f(unsigned short u) {
    return __uint_as_float(((unsigned)u) << 16);
}
// packed f32x2 -> bf16x2 (RTNE), single HW instr
__device__ __forceinline__ unsigned cvtpk(float lo, float hi_) {
    unsigned r;
    asm("v_cvt_pk_bf16_f32 %0, %1, %2" : "=v"(r) : "v"(lo), "v"(hi_));
    return r;
}

// async 16B global -> LDS (dest: wave-uniform base + lane*16; src: per-lane)
__device__ __forceinline__ void async_ld16(void* ldsdst, const void* gsrc) {
    __builtin_amdgcn_global_load_lds(
        (const __attribute__((address_space(1))) unsigned int*)gsrc,
        (__attribute__((address_space(3))) unsigned int*)ldsdst, 16, 0, 0);
}

// ---------------------------------------------------------------------------
// f32 -> bf16 convert, 4 elems/thread
// ---------------------------------------------------------------------------
__global__ __launch_bounds__(256) void cvtk(const float* __restrict__ in,
                                            unsigned short* __restrict__ out, int n4) {
    int i = blockIdx.x * 256 + threadIdx.x;
    if (i < n4) {
        float4 v = ((const float4*)in)[i];
        ushort4 o;
        o.x = f2bf(v.x); o.y = f2bf(v.y); o.z = f2bf(v.z); o.w = f2bf(v.w);
        ((ushort4*)out)[i] = o;
    }
}

// ---------------------------------------------------------------------------
// RoPE tables (f32): cos/sin[t][j], j<32 real freqs; j>=32 identity.
// ---------------------------------------------------------------------------
__global__ void rope_tables_k(float* __restrict__ cost, float* __restrict__ sint) {
    int idx = blockIdx.x * blockDim.x + threadIdx.x;
    if (idx >= T_ * 32) return;
    int t = idx >> 5, j = idx & 31;
    float e = (float)j * (1.0f / 31.0f);
    float freq = powf(1.0f / 1024.0f, e);
    float th = (float)t * freq;
    cost[idx] = cosf(th);
    sint[idx] = sinf(th);
}

// ---------------------------------------------------------------------------
// bf16 NT GEMM: C[M,N] = A[M,K] * B[N,K]^T, 128x128 tile, BK=64, 4 waves 2x2.
// (unchanged — verified)
// ---------------------------------------------------------------------------
__global__ __launch_bounds__(256) void gemm_bf16_nt(
    const unsigned short* __restrict__ A, const unsigned short* __restrict__ Bw,
    float* __restrict__ Cf, unsigned short* __restrict__ Cb,
    int M, int N, int K) {
    __shared__ __align__(16) unsigned short As[128 * 64];
    __shared__ __align__(16) unsigned short Bs[128 * 64];
    const int tid = threadIdx.x;
    const int l = tid & 63, w = tid >> 6;
    const int g = l >> 4, q16 = l & 15;

    int nwg = gridDim.x * gridDim.y;
    int lin = blockIdx.y * gridDim.x + blockIdx.x;
    int swz = (lin & 7) * (nwg >> 3) + (lin >> 3);
    int bx = swz % gridDim.x, by = swz / gridDim.x;
    const size_t m0 = (size_t)by * 128, n0 = (size_t)bx * 128;
    const int wm = (w >> 1) * 64, wn = (w & 1) * 64;

    f32x4 acc[4][4];
#pragma unroll
    for (int i = 0; i < 4; ++i)
#pragma unroll
        for (int j = 0; j < 4; ++j) acc[i][j] = (f32x4){0.f, 0.f, 0.f, 0.f};

    const int srow = l >> 3;
    const int schunk = (l & 7) ^ (srow & 7);
    const unsigned short* aBase = A + (m0 + srow) * (size_t)K + schunk * 8;
    const unsigned short* bBase = Bw + (n0 + srow) * (size_t)K + schunk * 8;
    const int roff = q16 & 7;

    for (int k0 = 0; k0 < K; k0 += 64) {
#pragma unroll
        for (int i = 0; i < 4; ++i) {
            size_t rstep = (size_t)(w * 4 + i) * 8 * K;
            async_ld16(&As[(w * 4 + i) * 512], aBase + rstep + k0);
            async_ld16(&Bs[(w * 4 + i) * 512], bBase + rstep + k0);
        }
        __syncthreads();
        __builtin_amdgcn_s_setprio(1);
#pragma unroll
        for (int ks = 0; ks < 2; ++ks) {
            bf16x8 af[4], bf[4];
#pragma unroll
            for (int f = 0; f < 4; ++f) {
                int off = (ks * 32 + g * 8) ^ (roff << 3);
                af[f] = *(const bf16x8*)&As[(wm + f * 16 + q16) * 64 + off];
                bf[f] = *(const bf16x8*)&Bs[(wn + f * 16 + q16) * 64 + off];
            }
#pragma unroll
            for (int fm = 0; fm < 4; ++fm)
#pragma unroll
                for (int fn = 0; fn < 4; ++fn)
                    acc[fm][fn] = __builtin_amdgcn_mfma_f32_16x16x32_bf16(
                        af[fm], bf[fn], acc[fm][fn], 0, 0, 0);
        }
        __builtin_amdgcn_s_setprio(0);
        __syncthreads();
    }

    if (Cb) {
#pragma unroll
        for (int fm = 0; fm < 4; ++fm)
#pragma unroll
            for (int r = 0; r < 4; ++r) {
                size_t base = (m0 + wm + fm * 16 + 4 * g + r) * (size_t)N + n0 + wn + q16;
#pragma unroll
                for (int fn = 0; fn < 4; ++fn)
                    Cb[base + fn * 16] = f2bf(acc[fm][fn][r]);
            }
    } else {
#pragma unroll
        for (int fm = 0; fm < 4; ++fm)
#pragma unroll
            for (int r = 0; r < 4; ++r) {
                size_t base = (m0 + wm + fm * 16 + 4 * g + r) * (size_t)N + n0 + wn + q16;
#pragma unroll
                for (int fn = 0; fn < 4; ++fn)
                    Cf[base + fn * 16] = acc[fm][fn][r];
            }
    }
}

// ---------------------------------------------------------------------------
// Pointwise prep on q,k only (in-place): RMSNorm + RoPE; q additionally
// pre-scaled by ATTN_SCALE (folded out of the attention kernel).
// ---------------------------------------------------------------------------
__global__ __launch_bounds__(256) void qkv_prep_k(
    unsigned short* __restrict__ qkv,
    const float* __restrict__ cost, const float* __restrict__ sint) {
    const int gw = (blockIdx.x * 256 + threadIdx.x) >> 6;
    const int lane = threadIdx.x & 63;
    const int h = gw & (H_ - 1);
    const int t = (gw / H_) & (T_ - 1);
    const int b = gw / (H_ * T_);
    const size_t rowbase = ((size_t)(b * T_ + t) * 3) * HDIM_ + (size_t)h * D_;
    const float c = (lane < 32) ? cost[t * 32 + lane] : 1.0f;
    const float s = (lane < 32) ? sint[t * 32 + lane] : 0.0f;
    const float EPS = 1.1920928955078125e-07f;

#pragma unroll
    for (int qk = 0; qk < 2; ++qk) {
        unsigned short* p = qkv + rowbase + (size_t)qk * HDIM_;
        float x1 = bf2f(p[lane]), x2 = bf2f(p[lane + 64]);
        float ss = x1 * x1 + x2 * x2;
#pragma unroll
        for (int m = 32; m >= 1; m >>= 1) ss += __shfl_xor(ss, m, 64);
        float r = 1.0f / sqrtf(ss * (1.0f / 128.0f) + EPS);
        x1 *= r; x2 *= r;
        float o1 = x1 * c + x2 * s;
        float o2 = x2 * c - x1 * s;
        if (qk == 0) { o1 *= ATTN_SCALE; o2 *= ATTN_SCALE; }
        p[lane]      = f2bf(o1);
        p[lane + 64] = f2bf(o2);
    }
}

// ---------------------------------------------------------------------------
// V blend + transpose -> vT[b][h][d][t]. (unchanged)
// ---------------------------------------------------------------------------
__global__ __launch_bounds__(256) void vtrans_k(
    const unsigned short* __restrict__ qkv, const float* __restrict__ ve,
    const float* __restrict__ lambdas, unsigned short* __restrict__ vT) {
    __shared__ unsigned short lds[64][65];
    const int tid = threadIdx.x;
    const int d0 = blockIdx.x * 64, t0 = blockIdx.y * 64;
    const int p = blockIdx.z;
    const int h = p & 7, b = p >> 3;
    const float l0 = lambdas[0], l1 = lambdas[1];

#pragma unroll
    for (int u = 0; u < 2; ++u) {
        int unit = tid + u * 256;
        int i = unit >> 3, jc = (unit & 7) * 8;
        size_t row = (size_t)(b * T_ + t0 + i);
        ushort8 vv = *(const ushort8*)&qkv[(row * 3 + 2) * HDIM_ + h * D_ + d0 + jc];
        const float* pe = &ve[row * HDIM_ + h * D_ + d0 + jc];
        float4 e0 = *(const float4*)pe;
        float4 e1 = *(const float4*)(pe + 4);
        lds[i][jc + 0] = f2bf(l0 * bf2f(vv[0]) + l1 * e0.x);
        lds[i][jc + 1] = f2bf(l0 * bf2f(vv[1]) + l1 * e0.y);
        lds[i][jc + 2] = f2bf(l0 * bf2f(vv[2]) + l1 * e0.z);
        lds[i][jc + 3] = f2bf(l0 * bf2f(vv[3]) + l1 * e0.w);
        lds[i][jc + 4] = f2bf(l0 * bf2f(vv[4]) + l1 * e1.x);
        lds[i][jc + 5] = f2bf(l0 * bf2f(vv[5]) + l1 * e1.y);
        lds[i][jc + 6] = f2bf(l0 * bf2f(vv[6]) + l1 * e1.z);
        lds[i][jc + 7] = f2bf(l0 * bf2f(vv[7]) + l1 * e1.w);
    }
    __syncthreads();
#pragma unroll
    for (int u = 0; u < 2; ++u) {
        int unit = tid + u * 256;
        int r = unit >> 3, tc = (unit & 7) * 8;
        ushort8 o;
#pragma unroll
        for (int m = 0; m < 8; ++m) o[m] = lds[tc + m][r];
        *(ushort8*)&vT[((size_t)(b * H_ + h) * D_ + d0 + r) * T_ + t0 + tc] = o;
    }
}

// ---------------------------------------------------------------------------
// MFMA flash attention, 32x32x16, SOFTWARE-PIPELINED:
//   phase t: bar; STAGE K(t+1),V(t); QK^T(t) [MFMA]; softmax(t-1) [VALU,
//   overlaps pending MFMA]; PV(t-1) [MFMA]. V staging staggered one phase
//   after K so plain double-buffering is race-free with ONE barrier/tile.
// 2x-unrolled so all LDS buffer indices are compile-time literals.
// Equal-length co-residency: blocks bid and bid+256 share qt.
// LDS 64KB -> 2 blocks/CU.
// ---------------------------------------------------------------------------
__global__ __launch_bounds__(256, 2) void attn_mfma(
    const unsigned short* __restrict__ qkv, const unsigned short* __restrict__ vT,
    unsigned short* __restrict__ y) {
    __shared__ __align__(16) unsigned short Ks[2][64 * 128];   // [kv][d]
    __shared__ __align__(16) unsigned short Vs[2][128 * 64];   // [d][kv]

    const int tid = threadIdx.x;
    const int l = tid & 63, w = tid >> 6;       // 4 waves
    const int l31 = l & 31, hi = l >> 5, l7 = l & 7;
    const int bid = blockIdx.x;
    const int xcd = bid & 7, slot = bid >> 3;
    const int pord = slot >> 4, qo = slot & 15;
    const int p = pord * 8 + xcd;               // 4 (b,h) per XCD (L2-fit)
    const int h = p & 7, b = p >> 3;
    const int qt = 15 - qo;                     // EQUAL for (bid, bid+256)
    const int q0 = qt * 128;

    // staging pointers: wave w owns LDS units w*4+i
    const unsigned short* kp[4];
    const unsigned short* vp[4];
#pragma unroll
    for (int i = 0; i < 4; ++i) {
        int r = 16 * w + 4 * i + (l >> 4);      // kv row in tile
        int kch = (l & 15) ^ (r & 7);
        kp[i] = &qkv[((size_t)(b * T_ + r) * 3 + 1) * HDIM_ + h * D_ + kch * 8];
        int d = 32 * w + 8 * i + (l >> 3);      // d row
        int vch = l7 ^ (d & 7);
        vp[i] = &vT[((size_t)(b * H_ + h) * D_ + d) * T_ + vch * 8];
    }
#define STAGE_K(buf, it_) do {                                         \
        size_t ko_ = (size_t)(it_) * (64 * 3 * HDIM_);                 \
        _Pragma("unroll")                                              \
        for (int i_ = 0; i_ < 4; ++i_)                                 \
            async_ld16(&Ks[buf][(w * 4 + i_) * 512], kp[i_] + ko_);    \
    } while (0)
#define STAGE_V(buf, it_) do {                                         \
        int vo_ = (it_) * 64;                                          \
        _Pragma("unroll")                                              \
        for (int i_ = 0; i_ < 4; ++i_)                                 \
            async_ld16(&Vs[buf][(w * 4 + i_) * 512], vp[i_] + vo_);    \
    } while (0)

    // Q fragments (B-operand): lane q-col qc (pre-scaled in prep)
    const int qc = q0 + w * 32 + l31;
    const size_t qbase = ((size_t)(b * T_ + qc) * 3) * HDIM_ + (size_t)h * D_;
    bf16x8 qf[8];
#pragma unroll
    for (int ks = 0; ks < 8; ++ks)
        qf[ks] = *(const bf16x8*)&qkv[qbase + ks * 16 + hi * 8];

    f32x16 accO[4];
#pragma unroll
    for (int i = 0; i < 4; ++i) accO[i] = (f32x16)(0.f);
    float m_s = -1e30f, l_s = 0.f;
    bf16x8 pb[4];

#define QKT_RAW(kbase, S0V, S1V) do {                                        \
    __builtin_amdgcn_s_setprio(1);                                           \
    S0V = (f32x16)(0.f); S1V = (f32x16)(0.f);                                \
    _Pragma("unroll")                                                        \
    for (int ks_ = 0; ks_ < 8; ++ks_) {                                      \
        int co_ = 8 * ((2 * ks_ + hi) ^ l7);                                 \
        bf16x8 k0_ = *(const bf16x8*)&(kbase)[l31 * 128 + co_];              \
        bf16x8 k1_ = *(const bf16x8*)&(kbase)[(32 + l31) * 128 + co_];       \
        S0V = __builtin_amdgcn_mfma_f32_32x32x16_bf16(k0_, qf[ks_], S0V, 0, 0, 0); \
        S1V = __builtin_amdgcn_mfma_f32_32x32x16_bf16(k1_, qf[ks_], S1V, 0, 0, 0); \
    }                                                                        \
    __builtin_amdgcn_s_setprio(0);                                           \
} while (0)

#define PACK_HALF(SV, MT) do {                                               \
    unsigned w0_[4], w1_[4], sw0_[4], sw1_[4];                               \
    _Pragma("unroll")                                                        \
    for (int s_ = 0; s_ < 4; ++s_) {                                         \
        w0_[s_] = cvtpk(SV[4 * s_ + 0], SV[4 * s_ + 1]);                     \
        w1_[s_] = cvtpk(SV[4 * s_ + 2], SV[4 * s_ + 3]);                     \
    }                                                                        \
    _Pragma("unroll")                                                        \
    for (int s_ = 0; s_ < 4; ++s_) {                                         \
        sw0_[s_] = __shfl_xor(w0_[s_], 32);                                  \
        sw1_[s_] = __shfl_xor(w1_[s_], 32);                                  \
    }                                                                        \
    _Pragma("unroll")                                                        \
    for (int kt_ = 0; kt_ < 2; ++kt_) {                                      \
        union { unsigned u[4]; bf16x8 v; } pu_;                              \
        pu_.u[0] = hi ? sw0_[2 * kt_ + 1] : w0_[2 * kt_];                    \
        pu_.u[1] = hi ? sw1_[2 * kt_ + 1] : w1_[2 * kt_];                    \
        pu_.u[2] = hi ? w0_[2 * kt_ + 1] : sw0_[2 * kt_];                    \
        pu_.u[3] = hi ? w1_[2 * kt_ + 1] : sw1_[2 * kt_];                    \
        pb[(MT) * 2 + kt_] = pu_.v;                                          \
    }                                                                        \
} while (0)

#define SM_MASK_PACK(S0V, S1V, kv0_) do {                                    \
    float sa_[16], sb_[16];                                                  \
    const bool edge_ = ((kv0_) + 64 > q0);                                   \
    _Pragma("unroll")                                                        \
    for (int r_ = 0; r_ < 16; ++r_) {                                        \
        float x0_ = S0V[r_], x1_ = S1V[r_];                                  \
        if (edge_) {                                                         \
            int kg_ = (kv0_) + (r_ & 3) + 8 * (r_ >> 2) + 4 * hi;            \
            if (kg_ > qc) x0_ = -1e30f;                                      \
            if (kg_ + 32 > qc) x1_ = -1e30f;                                 \
        }                                                                    \
        sa_[r_] = x0_; sb_[r_] = x1_;                                        \
    }                                                                        \
    float pm_ = -1e30f;                                                      \
    _Pragma("unroll")                                                        \
    for (int r_ = 0; r_ < 16; ++r_)                                          \
        pm_ = fmaxf(pm_, fmaxf(sa_[r_], sb_[r_]));                           \
    pm_ = fmaxf(pm_, __shfl_xor(pm_, 32));                                   \
    if (!__all(pm_ - m_s <= 8.0f)) {                                         \
        float mn_ = fmaxf(m_s, pm_);                                         \
        float sc_ = __expf(m_s - mn_);                                       \
        m_s = mn_; l_s *= sc_;                                               \
        _Pragma("unroll")                                                    \
        for (int dt_ = 0; dt_ < 4; ++dt_) accO[dt_] *= sc_;                  \
    }                                                                        \
    float rs_ = 0.f;                                                         \
    _Pragma("unroll")                                                        \
    for (int r_ = 0; r_ < 16; ++r_) {                                        \
        sa_[r_] = __expf(sa_[r_] - m_s); rs_ += sa_[r_];                     \
        sb_[r_] = __expf(sb_[r_] - m_s); rs_ += sb_[r_];                     \
    }                                                                        \
    rs_ += __shfl_xor(rs_, 32);                                              \
    l_s += rs_;                                                              \
    PACK_HALF(sa_, 0);                                                       \
    PACK_HALF(sb_, 1);                                                       \
} while (0)

#define PV_ACC(vbase) do {                                                   \
    __builtin_amdgcn_s_setprio(1);                                           \
    _Pragma("unroll")                                                        \
    for (int dt_ = 0; dt_ < 4; ++dt_) {                                      \
        int dr_ = dt_ * 32 + l31;                                            \
        _Pragma("unroll")                                                    \
        for (int kt_ = 0; kt_ < 4; ++kt_) {                                  \
            bf16x8 vf_ = *(const bf16x8*)&(vbase)[dr_ * 64 + 8 * ((2 * kt_ + hi) ^ l7)]; \
            accO[dt_] = __builtin_amdgcn_mfma_f32_32x32x16_bf16(vf_, pb[kt_], accO[dt_], 0, 0, 0); \
        }                                                                    \
    }                                                                        \
    __builtin_amdgcn_s_setprio(0);                                           \
} while (0)

    const int nkv = 2 * qt + 2;   // even, >= 2
    f32x16 sX0, sX1, sY0, sY1;

    // prologue: tile0 K; bar; tile1 K + tile0 V; QK^T(0) -> X
    STAGE_K(0, 0);
    __syncthreads();
    STAGE_K(1, 1);
    STAGE_V(0, 0);
    QKT_RAW(&Ks[0][0], sX0, sX1);

    int t = 1;
    while (t + 1 < nkv) {
        // phase A (tile t, odd): finish tile t-1
        __syncthreads();
        STAGE_K(0, t + 1);
        STAGE_V(1, t);
        QKT_RAW(&Ks[1][0], sY0, sY1);
        SM_MASK_PACK(sX0, sX1, (t - 1) * 64);
        PV_ACC(&Vs[0][0]);
        // phase B (tile t+1, even): finish tile t
        __syncthreads();
        if (t + 2 < nkv) STAGE_K(1, t + 2);
        STAGE_V(0, t + 1);
        QKT_RAW(&Ks[0][0], sX0, sX1);
        SM_MASK_PACK(sY0, sY1, t * 64);
        PV_ACC(&Vs[1][0]);
        t += 2;
    }
    // tail: t == nkv-1 (odd): last tile
    __syncthreads();
    STAGE_V(1, t);
    QKT_RAW(&Ks[1][0], sY0, sY1);
    SM_MASK_PACK(sX0, sX1, (t - 1) * 64);
    PV_ACC(&Vs[0][0]);
    __syncthreads();              // drain V(t) stage
    SM_MASK_PACK(sY0, sY1, t * 64);
    PV_ACC(&Vs[1][0]);

#undef STAGE_K
#undef STAGE_V
#undef QKT_RAW
#undef PACK_HALF
#undef SM_MASK_PACK
#undef PV_ACC

    // epilogue: y[b, qc, h*128 + d] = O / l
    float inv = 1.0f / l_s;
    const size_t yb = (size_t)(b * T_ + qc) * HDIM_ + (size_t)h * D_;
#pragma unroll
    for (int dt = 0; dt < 4; ++dt)
#pragma unroll
        for (int s = 0; s < 4; ++s) {
            ushort4 o;
            o.x = f2bf(accO[dt][4 * s + 0] * inv);
            o.y = f2bf(accO[dt][4 * s + 1] * inv);
            o.z = f2bf(accO[dt][4 * s + 2] * inv);
            o.w = f2bf(accO[dt][4 * s + 3] * inv);
            *(ushort4*)&y[yb + dt * 32 + 8 * s + 4 * hi] = o;
        }
}

// ---------------------------------------------------------------------------
// Workspace (bytes):
//   qkv bf16 [0,48M)  y [48M,64M)  xb [64M,80M)  wb [80M,86M)  pb [86M,88M)
//   cos/sin f32 [88M,88.5M)  vT bf16 [96M,112M)
// ---------------------------------------------------------------------------
extern "C" void kernel_launch(void* const* d_in, const int* in_sizes, int n_in,
                              void* d_out, int out_size, void* d_ws, size_t ws_size,
                              hipStream_t stream) {
    (void)in_sizes; (void)n_in; (void)out_size; (void)ws_size;
    const float* x        = (const float*)d_in[0];
    const float* ve       = (const float*)d_in[1];
    const float* qkv_w    = (const float*)d_in[2];
    const float* lambdas  = (const float*)d_in[3];
    const float* c_proj_w = (const float*)d_in[4];
    float* out = (float*)d_out;

    char* ws = (char*)d_ws;
    unsigned short* qkv = (unsigned short*)ws;                             // 8192*3072
    unsigned short* y   = (unsigned short*)(ws + 50331648);                // 8192*1024
    unsigned short* xb  = (unsigned short*)(ws + 67108864);                // 8192*1024
    unsigned short* wb  = (unsigned short*)(ws + 83886080);                // 3072*1024
    unsigned short* pb  = (unsigned short*)(ws + 90177536);                // 1024*1024
    float* cost = (float*)(ws + 92274688);                                 // 2048*32
    float* sint = cost + T_ * 32;
    unsigned short* vT  = (unsigned short*)(ws + 100663296);               // 32*128*2048

    hipLaunchKernelGGL(cvtk, dim3(8192), dim3(256), 0, stream, x, xb, 8192 * 1024 / 4);
    hipLaunchKernelGGL(cvtk, dim3(3072), dim3(256), 0, stream, qkv_w, wb, 3072 * 1024 / 4);
    hipLaunchKernelGGL(cvtk, dim3(1024), dim3(256), 0, stream, c_proj_w, pb, 1024 * 1024 / 4);
    hipLaunchKernelGGL(rope_tables_k, dim3(256), dim3(256), 0, stream, cost, sint);

    hipLaunchKernelGGL(gemm_bf16_nt, dim3(24, 64), dim3(256), 0, stream,
                       xb, wb, (float*)nullptr, qkv, B_ * T_, 3 * HDIM_, DIM_);
    hipLaunchKernelGGL(qkv_prep_k, dim3(B_ * T_ * H_ / 4), dim3(256), 0, stream,
                       qkv, cost, sint);
    hipLaunchKernelGGL(vtrans_k, dim3(2, 32, 32), dim3(256), 0, stream,
                       qkv, ve, lambdas, vT);
    hipLaunchKernelGGL(attn_mfma, dim3(512), dim3(256), 0, stream, qkv, vT, y);
    hipLaunchKernelGGL(gemm_bf16_nt, dim3(8, 64), dim3(256), 0, stream,
                       y, pb, out, (unsigned short*)nullptr, B_ * T_, DIM_, HDIM_);
}

// Round 9
// 312.289 us; speedup vs baseline: 1.0798x; 1.0798x over previous
//
#include <hip/hip_runtime.h>
#include <hip/hip_bf16.h>

constexpr int B_ = 4;
constexpr int T_ = 2048;
constexpr int DIM_ = 1024;
constexpr int H_ = 8;
constexpr int D_ = 128;
constexpr int HDIM_ = H_ * D_;   // 1024

typedef __attribute__((ext_vector_type(8))) short bf16x8;
typedef __attribute__((ext_vector_type(8))) unsigned short ushort8;
typedef __attribute__((ext_vector_type(4))) float f32x4;
typedef __attribute__((ext_vector_type(16))) float f32x16;

#define ATTN_SCALE 0.08838834764831845f

__device__ __forceinline__ unsigned short f2bf(float x) {
    unsigned u = __float_as_uint(x);
    unsigned r = (u + 0x7FFFu + ((u >> 16) & 1u)) >> 16;
    return (unsigned short)r;
}
__device__ __forceinline__ float bf2f(unsigned short u) {
    return __uint_as_float(((unsigned)u) << 16);
}
// packed f32x2 -> bf16x2 (RTNE), single HW instr
__device__ __forceinline__ unsigned cvtpk(float lo, float hi_) {
    unsigned r;
    asm("v_cvt_pk_bf16_f32 %0, %1, %2" : "=v"(r) : "v"(lo), "v"(hi_));
    return r;
}

// async 16B global -> LDS (dest: wave-uniform base + lane*16; src: per-lane)
__device__ __forceinline__ void async_ld16(void* ldsdst, const void* gsrc) {
    __builtin_amdgcn_global_load_lds(
        (const __attribute__((address_space(1))) unsigned int*)gsrc,
        (__attribute__((address_space(3))) unsigned int*)ldsdst, 16, 0, 0);
}

// ---------------------------------------------------------------------------
// f32 -> bf16 convert, 4 elems/thread
// ---------------------------------------------------------------------------
__global__ __launch_bounds__(256) void cvtk(const float* __restrict__ in,
                                            unsigned short* __restrict__ out, int n4) {
    int i = blockIdx.x * 256 + threadIdx.x;
    if (i < n4) {
        float4 v = ((const float4*)in)[i];
        ushort4 o;
        o.x = f2bf(v.x); o.y = f2bf(v.y); o.z = f2bf(v.z); o.w = f2bf(v.w);
        ((ushort4*)out)[i] = o;
    }
}

// ---------------------------------------------------------------------------
// RoPE tables (f32): cos/sin[t][j], j<32 real freqs; j>=32 identity.
// ---------------------------------------------------------------------------
__global__ void rope_tables_k(float* __restrict__ cost, float* __restrict__ sint) {
    int idx = blockIdx.x * blockDim.x + threadIdx.x;
    if (idx >= T_ * 32) return;
    int t = idx >> 5, j = idx & 31;
    float e = (float)j * (1.0f / 31.0f);
    float freq = powf(1.0f / 1024.0f, e);
    float th = (float)t * freq;
    cost[idx] = cosf(th);
    sint[idx] = sinf(th);
}

// ---------------------------------------------------------------------------
// bf16 NT GEMM: C[M,N] = A[M,K] * B[N,K]^T, 128x128 tile, BK=64, 4 waves 2x2.
// (unchanged — verified)
// ---------------------------------------------------------------------------
__global__ __launch_bounds__(256) void gemm_bf16_nt(
    const unsigned short* __restrict__ A, const unsigned short* __restrict__ Bw,
    float* __restrict__ Cf, unsigned short* __restrict__ Cb,
    int M, int N, int K) {
    __shared__ __align__(16) unsigned short As[128 * 64];
    __shared__ __align__(16) unsigned short Bs[128 * 64];
    const int tid = threadIdx.x;
    const int l = tid & 63, w = tid >> 6;
    const int g = l >> 4, q16 = l & 15;

    int nwg = gridDim.x * gridDim.y;
    int lin = blockIdx.y * gridDim.x + blockIdx.x;
    int swz = (lin & 7) * (nwg >> 3) + (lin >> 3);
    int bx = swz % gridDim.x, by = swz / gridDim.x;
    const size_t m0 = (size_t)by * 128, n0 = (size_t)bx * 128;
    const int wm = (w >> 1) * 64, wn = (w & 1) * 64;

    f32x4 acc[4][4];
#pragma unroll
    for (int i = 0; i < 4; ++i)
#pragma unroll
        for (int j = 0; j < 4; ++j) acc[i][j] = (f32x4){0.f, 0.f, 0.f, 0.f};

    const int srow = l >> 3;
    const int schunk = (l & 7) ^ (srow & 7);
    const unsigned short* aBase = A + (m0 + srow) * (size_t)K + schunk * 8;
    const unsigned short* bBase = Bw + (n0 + srow) * (size_t)K + schunk * 8;
    const int roff = q16 & 7;

    for (int k0 = 0; k0 < K; k0 += 64) {
#pragma unroll
        for (int i = 0; i < 4; ++i) {
            size_t rstep = (size_t)(w * 4 + i) * 8 * K;
            async_ld16(&As[(w * 4 + i) * 512], aBase + rstep + k0);
            async_ld16(&Bs[(w * 4 + i) * 512], bBase + rstep + k0);
        }
        __syncthreads();
        __builtin_amdgcn_s_setprio(1);
#pragma unroll
        for (int ks = 0; ks < 2; ++ks) {
            bf16x8 af[4], bf[4];
#pragma unroll
            for (int f = 0; f < 4; ++f) {
                int off = (ks * 32 + g * 8) ^ (roff << 3);
                af[f] = *(const bf16x8*)&As[(wm + f * 16 + q16) * 64 + off];
                bf[f] = *(const bf16x8*)&Bs[(wn + f * 16 + q16) * 64 + off];
            }
#pragma unroll
            for (int fm = 0; fm < 4; ++fm)
#pragma unroll
                for (int fn = 0; fn < 4; ++fn)
                    acc[fm][fn] = __builtin_amdgcn_mfma_f32_16x16x32_bf16(
                        af[fm], bf[fn], acc[fm][fn], 0, 0, 0);
        }
        __builtin_amdgcn_s_setprio(0);
        __syncthreads();
    }

    if (Cb) {
#pragma unroll
        for (int fm = 0; fm < 4; ++fm)
#pragma unroll
            for (int r = 0; r < 4; ++r) {
                size_t base = (m0 + wm + fm * 16 + 4 * g + r) * (size_t)N + n0 + wn + q16;
#pragma unroll
                for (int fn = 0; fn < 4; ++fn)
                    Cb[base + fn * 16] = f2bf(acc[fm][fn][r]);
            }
    } else {
#pragma unroll
        for (int fm = 0; fm < 4; ++fm)
#pragma unroll
            for (int r = 0; r < 4; ++r) {
                size_t base = (m0 + wm + fm * 16 + 4 * g + r) * (size_t)N + n0 + wn + q16;
#pragma unroll
                for (int fn = 0; fn < 4; ++fn)
                    Cf[base + fn * 16] = acc[fm][fn][r];
            }
    }
}

// ---------------------------------------------------------------------------
// Pointwise prep on q,k only (in-place): RMSNorm + RoPE; q pre-scaled by
// ATTN_SCALE. (unchanged — verified)
// ---------------------------------------------------------------------------
__global__ __launch_bounds__(256) void qkv_prep_k(
    unsigned short* __restrict__ qkv,
    const float* __restrict__ cost, const float* __restrict__ sint) {
    const int gw = (blockIdx.x * 256 + threadIdx.x) >> 6;
    const int lane = threadIdx.x & 63;
    const int h = gw & (H_ - 1);
    const int t = (gw / H_) & (T_ - 1);
    const int b = gw / (H_ * T_);
    const size_t rowbase = ((size_t)(b * T_ + t) * 3) * HDIM_ + (size_t)h * D_;
    const float c = (lane < 32) ? cost[t * 32 + lane] : 1.0f;
    const float s = (lane < 32) ? sint[t * 32 + lane] : 0.0f;
    const float EPS = 1.1920928955078125e-07f;

#pragma unroll
    for (int qk = 0; qk < 2; ++qk) {
        unsigned short* p = qkv + rowbase + (size_t)qk * HDIM_;
        float x1 = bf2f(p[lane]), x2 = bf2f(p[lane + 64]);
        float ss = x1 * x1 + x2 * x2;
#pragma unroll
        for (int m = 32; m >= 1; m >>= 1) ss += __shfl_xor(ss, m, 64);
        float r = 1.0f / sqrtf(ss * (1.0f / 128.0f) + EPS);
        x1 *= r; x2 *= r;
        float o1 = x1 * c + x2 * s;
        float o2 = x2 * c - x1 * s;
        if (qk == 0) { o1 *= ATTN_SCALE; o2 *= ATTN_SCALE; }
        p[lane]      = f2bf(o1);
        p[lane + 64] = f2bf(o2);
    }
}

// ---------------------------------------------------------------------------
// V blend + transpose -> vT[b][h][d][t]. (unchanged)
// ---------------------------------------------------------------------------
__global__ __launch_bounds__(256) void vtrans_k(
    const unsigned short* __restrict__ qkv, const float* __restrict__ ve,
    const float* __restrict__ lambdas, unsigned short* __restrict__ vT) {
    __shared__ unsigned short lds[64][65];
    const int tid = threadIdx.x;
    const int d0 = blockIdx.x * 64, t0 = blockIdx.y * 64;
    const int p = blockIdx.z;
    const int h = p & 7, b = p >> 3;
    const float l0 = lambdas[0], l1 = lambdas[1];

#pragma unroll
    for (int u = 0; u < 2; ++u) {
        int unit = tid + u * 256;
        int i = unit >> 3, jc = (unit & 7) * 8;
        size_t row = (size_t)(b * T_ + t0 + i);
        ushort8 vv = *(const ushort8*)&qkv[(row * 3 + 2) * HDIM_ + h * D_ + d0 + jc];
        const float* pe = &ve[row * HDIM_ + h * D_ + d0 + jc];
        float4 e0 = *(const float4*)pe;
        float4 e1 = *(const float4*)(pe + 4);
        lds[i][jc + 0] = f2bf(l0 * bf2f(vv[0]) + l1 * e0.x);
        lds[i][jc + 1] = f2bf(l0 * bf2f(vv[1]) + l1 * e0.y);
        lds[i][jc + 2] = f2bf(l0 * bf2f(vv[2]) + l1 * e0.z);
        lds[i][jc + 3] = f2bf(l0 * bf2f(vv[3]) + l1 * e0.w);
        lds[i][jc + 4] = f2bf(l0 * bf2f(vv[4]) + l1 * e1.x);
        lds[i][jc + 5] = f2bf(l0 * bf2f(vv[5]) + l1 * e1.y);
        lds[i][jc + 6] = f2bf(l0 * bf2f(vv[6]) + l1 * e1.z);
        lds[i][jc + 7] = f2bf(l0 * bf2f(vv[7]) + l1 * e1.w);
    }
    __syncthreads();
#pragma unroll
    for (int u = 0; u < 2; ++u) {
        int unit = tid + u * 256;
        int r = unit >> 3, tc = (unit & 7) * 8;
        ushort8 o;
#pragma unroll
        for (int m = 0; m < 8; ++m) o[m] = lds[tc + m][r];
        *(ushort8*)&vT[((size_t)(b * H_ + h) * D_ + d0 + r) * T_ + t0 + tc] = o;
    }
}

// ---------------------------------------------------------------------------
// MFMA flash attention, 32x32x16, kv-SPLIT waves + uniform blocks.
// 512 thr = 8 waves = 4 q-groups (32 cols) x 2 kv-halves (32 rows of each
// 64-kv tile). Each block processes the complementary q-tile pair
// (qp, 15-qp) sequentially -> EVERY block is exactly 34 kv-steps.
// Grid 256 = 1 block/CU, 8 waves/CU sustained (2/SIMD), zero tail.
// Per wave per tile: 8 QK^T MFMA + softmax(16 vals) + 8 PV MFMA; P stays in
// registers. kv-half streams keep independent (m,l); flash-combined at the
// q-tile epilogue through LDS (reuses the K/V space).
// All-masked sub-streams self-heal: deferred-max rescale and the combine
// weight both collapse to exp(-1e30-m)=0.
// ---------------------------------------------------------------------------
__global__ __launch_bounds__(512, 2) void attn_mfma(
    const unsigned short* __restrict__ qkv, const unsigned short* __restrict__ vT,
    unsigned short* __restrict__ y) {
    // [buf][0]=K tile [kv][d], [buf][1]=V tile [d][kv]; 64 KB total
    __shared__ __align__(16) unsigned short smem[2][2][64 * 128];
    __shared__ float mlm[4][32], mll[4][32];   // half0's m,l per (qg, col)

    const int tid = threadIdx.x;
    const int l = tid & 63, w = tid >> 6;       // 8 waves
    const int l31 = l & 31, hi = l >> 5, l7 = l & 7;
    const int qg = w & 3, half = w >> 2;
    const int bid = blockIdx.x;
    const int xcd = bid & 7, slot = bid >> 3;   // 32 blocks per XCD
    const int pord = slot >> 3, qp = slot & 7;
    const int p = pord * 8 + xcd;               // 4 (b,h) per XCD (KV L2-fit)
    const int h = p & 7, b = p >> 3;

    // staging pointers: wave w owns LDS units w*2+i for both K and V
    const unsigned short* kp[2];
    const unsigned short* vp[2];
#pragma unroll
    for (int i = 0; i < 2; ++i) {
        int r = 8 * w + 4 * i + (l >> 4);       // kv row in tile
        int kch = (l & 15) ^ (r & 7);
        kp[i] = &qkv[((size_t)(b * T_ + r) * 3 + 1) * HDIM_ + h * D_ + kch * 8];
        int d = 16 * w + 8 * i + (l >> 3);      // d row
        int vch = l7 ^ (d & 7);
        vp[i] = &vT[((size_t)(b * H_ + h) * D_ + d) * T_ + vch * 8];
    }
#define STAGE(bufi, it_) do {                                              \
        size_t ko_ = (size_t)(it_) * (64 * 3 * HDIM_);                     \
        int vo_ = (it_) * 64;                                              \
        _Pragma("unroll")                                                  \
        for (int i_ = 0; i_ < 2; ++i_) {                                   \
            async_ld16(&smem[bufi][0][(w * 2 + i_) * 512], kp[i_] + ko_);  \
            async_ld16(&smem[bufi][1][(w * 2 + i_) * 512], vp[i_] + vo_);  \
        }                                                                  \
    } while (0)

    for (int pass = 0; pass < 2; ++pass) {
        const int qt = pass ? (15 - qp) : qp;
        const int q0 = qt * 128;
        const int qc = q0 + qg * 32 + l31;
        const size_t qbase = ((size_t)(b * T_ + qc) * 3) * HDIM_ + (size_t)h * D_;
        bf16x8 qf[8];
#pragma unroll
        for (int ks = 0; ks < 8; ++ks)
            qf[ks] = *(const bf16x8*)&qkv[qbase + ks * 16 + hi * 8];

        f32x16 accO[4];
#pragma unroll
        for (int i = 0; i < 4; ++i) accO[i] = (f32x16)(0.f);
        float m_s = -1e30f, l_s = 0.f;
        bf16x8 pb[2];

        const int nkv = 2 * qt + 2;
        int cur = 0;
        STAGE(0, 0);

        for (int t = 0; t < nkv; ++t) {
            __syncthreads();   // tile t staged; all waves done with buf cur^1
            if (t + 1 < nkv) STAGE(cur ^ 1, t + 1);

            // ---- S^T = K * Q^T : this wave's 32 kv rows (8 MFMA) ----
            const unsigned short* Kb = &smem[cur][0][0];
            const int row = half * 32 + l31;
            f32x16 S = (f32x16)(0.f);
            __builtin_amdgcn_s_setprio(1);
#pragma unroll
            for (int ks = 0; ks < 8; ++ks) {
                bf16x8 kf = *(const bf16x8*)&Kb[row * 128 + 8 * ((2 * ks + hi) ^ l7)];
                S = __builtin_amdgcn_mfma_f32_32x32x16_bf16(kf, qf[ks], S, 0, 0, 0);
            }
            __builtin_amdgcn_s_setprio(0);

            // ---- mask + online softmax over this wave's kv rows ----
            float sv[16];
            float pmax = -1e30f;
            const int kvbase = t * 64 + half * 32;
            const bool edge = (kvbase + 32 > q0 + qg * 32);
#pragma unroll
            for (int r = 0; r < 16; ++r) {
                float x = S[r];
                if (edge) {
                    int kg = kvbase + (r & 3) + 8 * (r >> 2) + 4 * hi;
                    if (kg > qc) x = -1e30f;
                }
                sv[r] = x;
                pmax = fmaxf(pmax, x);
            }
            pmax = fmaxf(pmax, __shfl_xor(pmax, 32));
            if (!__all(pmax - m_s <= 8.0f)) {
                float mn = fmaxf(m_s, pmax);
                float sc = __expf(m_s - mn);
                m_s = mn; l_s *= sc;
#pragma unroll
                for (int dt = 0; dt < 4; ++dt) accO[dt] *= sc;
            }
            float rs = 0.f;
#pragma unroll
            for (int r = 0; r < 16; ++r) {
                sv[r] = __expf(sv[r] - m_s);
                rs += sv[r];
            }
            rs += __shfl_xor(rs, 32);
            l_s += rs;

            // ---- repack P (C-regs) -> PV B-frags, in-register ----
            {
                unsigned w0[4], w1[4], sw0[4], sw1[4];
#pragma unroll
                for (int s = 0; s < 4; ++s) {
                    w0[s] = cvtpk(sv[4 * s + 0], sv[4 * s + 1]);
                    w1[s] = cvtpk(sv[4 * s + 2], sv[4 * s + 3]);
                }
#pragma unroll
                for (int s = 0; s < 4; ++s) {
                    sw0[s] = __shfl_xor(w0[s], 32);
                    sw1[s] = __shfl_xor(w1[s], 32);
                }
#pragma unroll
                for (int kt = 0; kt < 2; ++kt) {
                    union { unsigned u[4]; bf16x8 v; } pu;
                    pu.u[0] = hi ? sw0[2 * kt + 1] : w0[2 * kt];
                    pu.u[1] = hi ? sw1[2 * kt + 1] : w1[2 * kt];
                    pu.u[2] = hi ? w0[2 * kt + 1] : sw0[2 * kt];
                    pu.u[3] = hi ? w1[2 * kt + 1] : sw1[2 * kt];
                    pb[kt] = pu.v;
                }
            }

            // ---- PV: O += V^T * P over this wave's kv half (8 MFMA) ----
            const unsigned short* Vb = &smem[cur][1][0];
            __builtin_amdgcn_s_setprio(1);
#pragma unroll
            for (int dt = 0; dt < 4; ++dt) {
                int dr = dt * 32 + l31;
#pragma unroll
                for (int kt = 0; kt < 2; ++kt) {
                    int ktg = half * 2 + kt;
                    bf16x8 vf = *(const bf16x8*)&Vb[dr * 64 + 8 * ((2 * ktg + hi) ^ l7)];
                    accO[dt] = __builtin_amdgcn_mfma_f32_32x32x16_bf16(vf, pb[kt],
                                                                       accO[dt], 0, 0, 0);
                }
            }
            __builtin_amdgcn_s_setprio(0);
            cur ^= 1;
        }

        // ---- combine kv-halves + epilogue (LDS reused as f32 scratch) ----
        __syncthreads();                       // everyone done with smem tiles
        float* Cb = (float*)&smem[0][0][0];    // 4 qg x 32 q x 128 d = 64 KB
        if (half == 0) {
            mlm[qg][l31] = m_s;
            mll[qg][l31] = l_s;
#pragma unroll
            for (int dt = 0; dt < 4; ++dt)
#pragma unroll
                for (int r = 0; r < 16; ++r) {
                    int d = dt * 32 + (r & 3) + 8 * (r >> 2) + 4 * hi;
                    Cb[(qg * 32 + l31) * 128 + d] = accO[dt][r];
                }
        }
        __syncthreads();
        if (half == 1) {
            float mA = mlm[qg][l31], lA = mll[qg][l31];
            float mM = fmaxf(mA, m_s);
            float sA = __expf(mA - mM), sB = __expf(m_s - mM);
            float linv = 1.0f / (sA * lA + sB * l_s);
            const size_t yb = (size_t)(b * T_ + qc) * HDIM_ + (size_t)h * D_;
            const float* Crow = &Cb[(qg * 32 + l31) * 128];
#pragma unroll
            for (int dt = 0; dt < 4; ++dt)
#pragma unroll
                for (int s = 0; s < 4; ++s) {
                    int d0 = dt * 32 + 8 * s + 4 * hi;
                    ushort4 o;
                    o.x = f2bf((sA * Crow[d0 + 0] + sB * accO[dt][4 * s + 0]) * linv);
                    o.y = f2bf((sA * Crow[d0 + 1] + sB * accO[dt][4 * s + 1]) * linv);
                    o.z = f2bf((sA * Crow[d0 + 2] + sB * accO[dt][4 * s + 2]) * linv);
                    o.w = f2bf((sA * Crow[d0 + 3] + sB * accO[dt][4 * s + 3]) * linv);
                    *(ushort4*)&y[yb + d0] = o;
                }
        }
        __syncthreads();                       // protect smem before next pass
    }
#undef STAGE
}

// ---------------------------------------------------------------------------
// Workspace (bytes):
//   qkv bf16 [0,48M)  y [48M,64M)  xb [64M,80M)  wb [80M,86M)  pb [86M,88M)
//   cos/sin f32 [88M,88.5M)  vT bf16 [96M,112M)
// ---------------------------------------------------------------------------
extern "C" void kernel_launch(void* const* d_in, const int* in_sizes, int n_in,
                              void* d_out, int out_size, void* d_ws, size_t ws_size,
                              hipStream_t stream) {
    (void)in_sizes; (void)n_in; (void)out_size; (void)ws_size;
    const float* x        = (const float*)d_in[0];
    const float* ve       = (const float*)d_in[1];
    const float* qkv_w    = (const float*)d_in[2];
    const float* lambdas  = (const float*)d_in[3];
    const float* c_proj_w = (const float*)d_in[4];
    float* out = (float*)d_out;

    char* ws = (char*)d_ws;
    unsigned short* qkv = (unsigned short*)ws;                             // 8192*3072
    unsigned short* y   = (unsigned short*)(ws + 50331648);                // 8192*1024
    unsigned short* xb  = (unsigned short*)(ws + 67108864);                // 8192*1024
    unsigned short* wb  = (unsigned short*)(ws + 83886080);                // 3072*1024
    unsigned short* pb  = (unsigned short*)(ws + 90177536);                // 1024*1024
    float* cost = (float*)(ws + 92274688);                                 // 2048*32
    float* sint = cost + T_ * 32;
    unsigned short* vT  = (unsigned short*)(ws + 100663296);               // 32*128*2048

    hipLaunchKernelGGL(cvtk, dim3(8192), dim3(256), 0, stream, x, xb, 8192 * 1024 / 4);
    hipLaunchKernelGGL(cvtk, dim3(3072), dim3(256), 0, stream, qkv_w, wb, 3072 * 1024 / 4);
    hipLaunchKernelGGL(cvtk, dim3(1024), dim3(256), 0, stream, c_proj_w, pb, 1024 * 1024 / 4);
    hipLaunchKernelGGL(rope_tables_k, dim3(256), dim3(256), 0, stream, cost, sint);

    hipLaunchKernelGGL(gemm_bf16_nt, dim3(24, 64), dim3(256), 0, stream,
                       xb, wb, (float*)nullptr, qkv, B_ * T_, 3 * HDIM_, DIM_);
    hipLaunchKernelGGL(qkv_prep_k, dim3(B_ * T_ * H_ / 4), dim3(256), 0, stream,
                       qkv, cost, sint);
    hipLaunchKernelGGL(vtrans_k, dim3(2, 32, 32), dim3(256), 0, stream,
                       qkv, ve, lambdas, vT);
    hipLaunchKernelGGL(attn_mfma, dim3(256), dim3(512), 0, stream, qkv, vT, y);
    hipLaunchKernelGGL(gemm_bf16_nt, dim3(8, 64), dim3(256), 0, stream,
                       y, pb, out, (unsigned short*)nullptr, B_ * T_, DIM_, HDIM_);
}